// Round 1
// baseline (592.909 us; speedup 1.0000x reference)
//
#include <hip/hip_runtime.h>
#include <math.h>

// ---------------- workspace layout (float offsets) ----------------
#define WS_H      0                         // h padded to stride 256: 16384*256
#define WS_X1     (WS_H + 16384*256)        // x + gat, stride 200: 16384*200
#define WS_WPAD   (WS_X1 + 16384*200)       // gat_W zero-padded to 200x256
#define WS_W2T    (WS_WPAD + 200*256)       // conv2_w transposed [n][o*40+c]: 1024*1600
#define WS_Y3P    (WS_W2T + 1024*1600)      // conv2 partials [b][nt][1400]: 16*16*1400
#define WS_Y5     (WS_Y3P + 16*16*1400)     // flattened embedding: 16*1400
#define WS_Z      (WS_Y5 + 16*1400)         // 16*1024
#define WS_G      (WS_Z + 16384)            // gelu(z)
#define WS_Z2     (WS_G + 16384)            // z + gelu(z)@W2 + b2
#define WS_AS     (WS_Z2 + 16384)           // 1024
#define WS_AD     (WS_AS + 1024)            // 1024
#define WS_MAXS   (WS_AD + 1024)            // 1 (padded to 4)
#define WS_WEFF   (WS_MAXS + 4)             // 40*30 pooled conv1 kernel
#define WS_S1     (WS_WEFF + 1200)          // bn1 scale (40)
#define WS_SH1    (WS_S1 + 40)              // bn1 shift w/ conv1_b folded (40)
#define WS_S2     (WS_SH1 + 40)             // bn2 scale
#define WS_SH2    (WS_S2 + 40)              // bn2 shift w/ conv2_b folded
// total ~9.6M floats = ~38.4 MB

// ---------------- k0: small-parameter prep ----------------
__global__ void k0_prep(const float* __restrict__ gat_W,
                        const float* __restrict__ conv1_w, const float* __restrict__ conv1_b,
                        const float* __restrict__ bn1_g, const float* __restrict__ bn1_b,
                        const float* __restrict__ bn1_m, const float* __restrict__ bn1_v,
                        const float* __restrict__ conv2_b,
                        const float* __restrict__ bn2_g, const float* __restrict__ bn2_b,
                        const float* __restrict__ bn2_m, const float* __restrict__ bn2_v,
                        float* __restrict__ ws) {
  int t = threadIdx.x;
  float* wpad = ws + WS_WPAD;
  for (int i = t; i < 200 * 256; i += 256) {
    int k = i >> 8, c = i & 255;
    wpad[i] = (c < 200) ? gat_W[k * 200 + c] : 0.f;
  }
  if (t < 40) {
    // pooled conv1 kernel: weff[c][j] = (1/5) * sum_{t=0..4} conv1_w[c][j-t]
    float* weff = ws + WS_WEFF;
    for (int j = 0; j < 30; ++j) {
      float s = 0.f;
      for (int tt = 0; tt < 5; ++tt) {
        int k = j - tt;
        if (k >= 0 && k < 26) s += conv1_w[t * 26 + k];
      }
      weff[t * 30 + j] = s * 0.2f;
    }
    float s1 = bn1_g[t] * rsqrtf(bn1_v[t] + 1e-5f);
    ws[WS_S1 + t] = s1;
    ws[WS_SH1 + t] = bn1_b[t] + (conv1_b[t] - bn1_m[t]) * s1;
    float s2 = bn2_g[t] * rsqrtf(bn2_v[t] + 1e-5f);
    ws[WS_S2 + t] = s2;
    ws[WS_SH2 + t] = bn2_b[t] + (conv2_b[t] - bn2_m[t]) * s2;
  }
}

// ---------------- k0b: transpose conv2_w (1600 x 1024) -> (1024 x 1600) ----------------
__global__ __launch_bounds__(256) void k0b_transpose(const float* __restrict__ w2,
                                                     float* __restrict__ w2t) {
  __shared__ float tile[64][65];
  int rt = blockIdx.x * 64;  // oc dim (1600)
  int ct = blockIdx.y * 64;  // n dim (1024)
  for (int i = threadIdx.x; i < 4096; i += 256) {
    int r = i >> 6, c = i & 63;
    tile[r][c] = w2[(rt + r) * 1024 + ct + c];
  }
  __syncthreads();
  for (int i = threadIdx.x; i < 4096; i += 256) {
    int r = i >> 6, c = i & 63;
    w2t[(ct + r) * 1600 + rt + c] = tile[c][r];
  }
}

// ---------------- k1: h = x(16384x200) @ wpad(200x256), h stride 256 ----------------
__global__ __launch_bounds__(256) void k1_gemm_h(const float* __restrict__ x,
                                                 const float* __restrict__ wpad,
                                                 float* __restrict__ h) {
  __shared__ float As[8][64];
  __shared__ float Bs[8][64];
  int t = threadIdx.x;
  int tm = t & 15, tn = t >> 4;
  int row0 = blockIdx.x * 64;
  int col0 = blockIdx.y * 64;
  float acc[4][4] = {};
  for (int k0 = 0; k0 < 200; k0 += 8) {
    for (int i = t; i < 512; i += 256) {
      int m = i >> 3, k = i & 7;
      As[k][m] = x[(row0 + m) * 200 + k0 + k];
    }
    for (int i = t; i < 512; i += 256) {
      int k = i >> 6, n = i & 63;
      Bs[k][n] = wpad[(k0 + k) * 256 + col0 + n];
    }
    __syncthreads();
#pragma unroll
    for (int k = 0; k < 8; ++k) {
      float a[4], b[4];
#pragma unroll
      for (int i = 0; i < 4; ++i) a[i] = As[k][tm * 4 + i];
#pragma unroll
      for (int j = 0; j < 4; ++j) b[j] = Bs[k][tn * 4 + j];
#pragma unroll
      for (int i = 0; i < 4; ++i)
#pragma unroll
        for (int j = 0; j < 4; ++j) acc[i][j] += a[i] * b[j];
    }
    __syncthreads();
  }
#pragma unroll
  for (int i = 0; i < 4; ++i)
#pragma unroll
    for (int j = 0; j < 4; ++j)
      h[(row0 + tm * 4 + i) * 256 + col0 + tn * 4 + j] = acc[i][j];
}

// ---------------- k1b: attention scores a_s, a_d for rows < 1024 ----------------
__global__ void k1b_scores(const float* __restrict__ h, const float* __restrict__ att_src,
                           const float* __restrict__ att_dst, float* __restrict__ as_,
                           float* __restrict__ ad_) {
  int r = blockIdx.x * 256 + threadIdx.x;  // < 1024
  const float* hr = h + r * 256;
  float s = 0.f, d = 0.f;
  for (int f = 0; f < 200; ++f) {
    float v = hr[f];
    s += v * att_src[f];
    d += v * att_dst[f];
  }
  as_[r] = s;
  ad_[r] = d;
}

// ---------------- k1c: max over a_s ----------------
__global__ void k1c_max(const float* __restrict__ as_, float* __restrict__ maxs) {
  __shared__ float rb[256];
  int t = threadIdx.x;
  float m = -1e30f;
  for (int j = t; j < 1024; j += 256) m = fmaxf(m, as_[j]);
  rb[t] = m;
  __syncthreads();
  for (int s = 128; s > 0; s >>= 1) {
    if (t < s) rb[t] = fmaxf(rb[t], rb[t + s]);
    __syncthreads();
  }
  if (t == 0) maxs[0] = rb[0];
}

// ---------------- k2a: dense attention for graph 0 + x1 rows [0,1024) ----------------
__global__ __launch_bounds__(256) void k2a_attn(const float* __restrict__ x,
                                                const float* __restrict__ h,
                                                const float* __restrict__ as_,
                                                const float* __restrict__ ad_,
                                                const float* __restrict__ maxs_p,
                                                const float* __restrict__ gat_b,
                                                float* __restrict__ x1) {
  __shared__ float pbuf[4][1024];
  __shared__ float rb[256];
  __shared__ float dsh[4];
  int t = threadIdx.x;
  int i0 = blockIdx.x * 4;
  float maxs = maxs_p[0];
  float M[4], ad[4], dsum[4] = {0, 0, 0, 0};
#pragma unroll
  for (int ii = 0; ii < 4; ++ii) {
    ad[ii] = ad_[i0 + ii];
    float v = maxs + ad[ii];
    M[ii] = v >= 0.f ? v : 0.2f * v;
  }
  for (int j = t; j < 1024; j += 256) {
    float asj = as_[j];
#pragma unroll
    for (int ii = 0; ii < 4; ++ii) {
      float v = asj + ad[ii];
      float l = v >= 0.f ? v : 0.2f * v;
      float p = __expf(l - M[ii]);
      pbuf[ii][j] = p;
      dsum[ii] += p;
    }
  }
  __syncthreads();
  for (int ii = 0; ii < 4; ++ii) {
    rb[t] = dsum[ii];
    __syncthreads();
    for (int s = 128; s > 0; s >>= 1) {
      if (t < s) rb[t] += rb[t + s];
      __syncthreads();
    }
    if (t == 0) dsh[ii] = rb[0];
    __syncthreads();
  }
  if (t < 200) {
    float acc[4] = {0, 0, 0, 0};
    for (int j = 0; j < 1024; ++j) {
      float hv = h[j * 256 + t];
#pragma unroll
      for (int ii = 0; ii < 4; ++ii) acc[ii] += pbuf[ii][j] * hv;
    }
    float gb = gat_b[t];
#pragma unroll
    for (int ii = 0; ii < 4; ++ii) {
      int i = i0 + ii;
      x1[i * 200 + t] = x[i * 200 + t] + acc[ii] / dsh[ii] + gb;
    }
  }
}

// ---------------- k2b: x1 rows [1024,16384): x + h + gat_b ----------------
__global__ void k2b_x1rest(const float* __restrict__ x, const float* __restrict__ h,
                           const float* __restrict__ gat_b, float* __restrict__ x1) {
  int id = blockIdx.x * 256 + threadIdx.x;  // < 15360*50
  int r = 1024 + id / 50;
  int q = (id % 50) * 4;
  float4 xv = *(const float4*)(x + r * 200 + q);
  float4 hv = *(const float4*)(h + r * 256 + q);
  float4 gb = *(const float4*)(gat_b + q);
  float4 o;
  o.x = xv.x + hv.x + gb.x;
  o.y = xv.y + hv.y + gb.y;
  o.z = xv.z + hv.z + gb.z;
  o.w = xv.w + hv.w + gb.w;
  *(float4*)(x1 + r * 200 + q) = o;
}

// ---------------- k3: fused conv1(30-tap)+bn1+elu+conv2 partial reduce ----------------
// grid (16 b, 16 node-tiles of 64), block 320 (280 workers)
__global__ __launch_bounds__(320, 1) void k3_conv(const float* __restrict__ x1,
                                                  const float* __restrict__ w2t,
                                                  const float* __restrict__ ws,
                                                  float* __restrict__ y3p) {
  __shared__ __align__(16) float xbuf[200];
  __shared__ __align__(16) float w2ls[1600];
  __shared__ float tmpls[1400];
  int t = threadIdx.x;
  int b = blockIdx.x, nt = blockIdx.y;
  const float* weff = ws + WS_WEFF;
  int c = t / 7, pg = t % 7;  // c: channel for conv1 phase, output o for conv2 phase
  float wr[30];
  float s1c = 0.f, sh1c = 0.f;
  if (t < 280) {
#pragma unroll
    for (int j = 0; j < 30; ++j) wr[j] = weff[c * 30 + j];
    s1c = ws[WS_S1 + c];
    sh1c = ws[WS_SH1 + c];
  }
  float acc[5] = {0, 0, 0, 0, 0};
  for (int nn = 0; nn < 64; ++nn) {
    int n = nt * 64 + nn;
    const float4* xrow = (const float4*)(x1 + (b * 1024 + n) * 200);
    if (t < 50) ((float4*)xbuf)[t] = xrow[t];
    const float4* wsrc = (const float4*)(w2t + n * 1600);
    for (int i = t; i < 400; i += 320) ((float4*)w2ls)[i] = wsrc[i];
    __syncthreads();
    if (t < 280) {
      float xw[50];
#pragma unroll
      for (int i = 0; i < 50; ++i) xw[i] = xbuf[pg * 25 + i];
#pragma unroll
      for (int u = 0; u < 5; ++u) {
        float s = 0.f;
#pragma unroll
        for (int j = 0; j < 30; ++j) s += xw[u * 5 + j] * wr[j];
        float v = s * s1c + sh1c;
        tmpls[c * 35 + pg * 5 + u] = v > 0.f ? v : __expf(v) - 1.f;
      }
    }
    __syncthreads();
    if (t < 280) {
#pragma unroll 4
      for (int cc = 0; cc < 40; ++cc) {
        float wv = w2ls[c * 40 + cc];
#pragma unroll
        for (int u = 0; u < 5; ++u) acc[u] += tmpls[cc * 35 + pg * 5 + u] * wv;
      }
    }
    __syncthreads();
  }
  if (t < 280) {
    float* dst = y3p + (b * 16 + nt) * 1400 + c * 35 + pg * 5;
#pragma unroll
    for (int u = 0; u < 5; ++u) dst[u] = acc[u];
  }
}

// ---------------- k4: reduce partials + bn2 + elu + projc + rearrange -> y5 ----------------
__global__ __launch_bounds__(256) void k4_proj(const float* __restrict__ y3p,
                                               const float* __restrict__ ws,
                                               const float* __restrict__ projc_w,
                                               const float* __restrict__ projc_b,
                                               float* __restrict__ y5) {
  __shared__ float tls[1400];
  int t = threadIdx.x, b = blockIdx.x;
  for (int idx = t; idx < 1400; idx += 256) {
    float s = 0.f;
    for (int nt = 0; nt < 16; ++nt) s += y3p[(b * 16 + nt) * 1400 + idx];
    int o = idx / 35;
    float v = s * ws[WS_S2 + o] + ws[WS_SH2 + o];
    tls[idx] = v > 0.f ? v : __expf(v) - 1.f;
  }
  __syncthreads();
  for (int idx = t; idx < 1400; idx += 256) {
    int p = idx / 40, e = idx % 40;
    float acc = projc_b[e];
    for (int o = 0; o < 40; ++o) acc += tls[o * 35 + p] * projc_w[e * 40 + o];
    y5[b * 1400 + idx] = acc;  // idx = p*40+e matches 'b (h w) e' flatten
  }
}

// ---------------- k5: z = y5 @ W1 + b1 ; g = gelu_exact(z) ----------------
__global__ __launch_bounds__(256) void k5_fc1(const float* __restrict__ y5,
                                              const float* __restrict__ W1,
                                              const float* __restrict__ b1,
                                              float* __restrict__ z, float* __restrict__ g) {
  __shared__ __align__(16) float yls[8 * 1400];
  int t = threadIdx.x;
  int cb = blockIdx.x;  // 8 chunks of 128 cols
  int bh = blockIdx.y;  // 2 halves of 8 rows
  const float4* src = (const float4*)(y5 + bh * 8 * 1400);
  for (int i = t; i < 2800; i += 256) ((float4*)yls)[i] = src[i];
  __syncthreads();
  int nq = t & 31, bl = t >> 5;
  int n = cb * 128 + nq * 4;
  int b = bh * 8 + bl;
  float4 acc = *(const float4*)(b1 + n);
  const float* yrow = yls + bl * 1400;
  for (int k = 0; k < 1400; ++k) {
    float yv = yrow[k];
    float4 w = *(const float4*)(W1 + k * 1024 + n);
    acc.x += yv * w.x;
    acc.y += yv * w.y;
    acc.z += yv * w.z;
    acc.w += yv * w.w;
  }
  *(float4*)(z + b * 1024 + n) = acc;
  float4 gg;
  gg.x = 0.5f * acc.x * (1.f + erff(acc.x * 0.70710678f));
  gg.y = 0.5f * acc.y * (1.f + erff(acc.y * 0.70710678f));
  gg.z = 0.5f * acc.z * (1.f + erff(acc.z * 0.70710678f));
  gg.w = 0.5f * acc.w * (1.f + erff(acc.w * 0.70710678f));
  *(float4*)(g + b * 1024 + n) = gg;
}

// ---------------- k6: z2 = z + g @ W2 + b2 ----------------
__global__ __launch_bounds__(256) void k6_fc2(const float* __restrict__ g,
                                              const float* __restrict__ z,
                                              const float* __restrict__ W2,
                                              const float* __restrict__ b2,
                                              float* __restrict__ z2) {
  __shared__ __align__(16) float gls[8 * 1024];
  int t = threadIdx.x;
  int cb = blockIdx.x;
  int bh = blockIdx.y;
  const float4* src = (const float4*)(g + bh * 8192);
  for (int i = t; i < 2048; i += 256) ((float4*)gls)[i] = src[i];
  __syncthreads();
  int nq = t & 31, bl = t >> 5;
  int n = cb * 128 + nq * 4;
  int b = bh * 8 + bl;
  float4 acc = *(const float4*)(b2 + n);
  const float* grow = gls + bl * 1024;
  for (int k = 0; k < 1024; ++k) {
    float gv = grow[k];
    float4 w = *(const float4*)(W2 + k * 1024 + n);
    acc.x += gv * w.x;
    acc.y += gv * w.y;
    acc.z += gv * w.z;
    acc.w += gv * w.w;
  }
  float4 zv = *(const float4*)(z + b * 1024 + n);
  float4 o;
  o.x = zv.x + acc.x;
  o.y = zv.y + acc.y;
  o.z = zv.z + acc.z;
  o.w = zv.w + acc.w;
  *(float4*)(z2 + b * 1024 + n) = o;
}

// ---------------- k7: LayerNorm over last dim -> out ----------------
__global__ __launch_bounds__(256) void k7_ln(const float* __restrict__ z2,
                                             const float* __restrict__ ln_g,
                                             const float* __restrict__ ln_b,
                                             float* __restrict__ out) {
  __shared__ float r1[256], r2[256];
  int t = threadIdx.x, b = blockIdx.x;
  float4 v = *(const float4*)(z2 + b * 1024 + t * 4);
  r1[t] = v.x + v.y + v.z + v.w;
  r2[t] = v.x * v.x + v.y * v.y + v.z * v.z + v.w * v.w;
  __syncthreads();
  for (int s = 128; s > 0; s >>= 1) {
    if (t < s) {
      r1[t] += r1[t + s];
      r2[t] += r2[t + s];
    }
    __syncthreads();
  }
  float mu = r1[0] * (1.f / 1024.f);
  float var = r2[0] * (1.f / 1024.f) - mu * mu;
  float rstd = rsqrtf(var + 1e-5f);
  float4 gg = *(const float4*)(ln_g + t * 4);
  float4 bb = *(const float4*)(ln_b + t * 4);
  float4 o;
  o.x = (v.x - mu) * rstd * gg.x + bb.x;
  o.y = (v.y - mu) * rstd * gg.y + bb.y;
  o.z = (v.z - mu) * rstd * gg.z + bb.z;
  o.w = (v.w - mu) * rstd * gg.w + bb.w;
  *(float4*)(out + b * 1024 + t * 4) = o;
}

extern "C" void kernel_launch(void* const* d_in, const int* in_sizes, int n_in,
                              void* d_out, int out_size, void* d_ws, size_t ws_size,
                              hipStream_t stream) {
  (void)in_sizes; (void)n_in; (void)out_size; (void)ws_size;
  const float* x       = (const float*)d_in[0];
  const float* gat_W   = (const float*)d_in[1];
  const float* att_src = (const float*)d_in[2];
  const float* att_dst = (const float*)d_in[3];
  const float* gat_b   = (const float*)d_in[4];
  const float* conv1_w = (const float*)d_in[5];
  const float* conv1_b = (const float*)d_in[6];
  const float* bn1_g   = (const float*)d_in[7];
  const float* bn1_b   = (const float*)d_in[8];
  const float* bn1_m   = (const float*)d_in[9];
  const float* bn1_v   = (const float*)d_in[10];
  const float* conv2_w = (const float*)d_in[11];
  const float* conv2_b = (const float*)d_in[12];
  const float* bn2_g   = (const float*)d_in[13];
  const float* bn2_b   = (const float*)d_in[14];
  const float* bn2_m   = (const float*)d_in[15];
  const float* bn2_v   = (const float*)d_in[16];
  const float* projc_w = (const float*)d_in[17];
  const float* projc_b = (const float*)d_in[18];
  const float* W1      = (const float*)d_in[19];
  const float* b1      = (const float*)d_in[20];
  const float* W2      = (const float*)d_in[21];
  const float* b2      = (const float*)d_in[22];
  const float* ln_g    = (const float*)d_in[23];
  const float* ln_b    = (const float*)d_in[24];
  float* ws  = (float*)d_ws;
  float* out = (float*)d_out;

  hipLaunchKernelGGL(k0_prep, dim3(1), dim3(256), 0, stream, gat_W, conv1_w, conv1_b,
                     bn1_g, bn1_b, bn1_m, bn1_v, conv2_b, bn2_g, bn2_b, bn2_m, bn2_v, ws);
  hipLaunchKernelGGL(k0b_transpose, dim3(25, 16), dim3(256), 0, stream, conv2_w, ws + WS_W2T);
  hipLaunchKernelGGL(k1_gemm_h, dim3(256, 4), dim3(256), 0, stream, x, ws + WS_WPAD, ws + WS_H);
  hipLaunchKernelGGL(k1b_scores, dim3(4), dim3(256), 0, stream, ws + WS_H, att_src, att_dst,
                     ws + WS_AS, ws + WS_AD);
  hipLaunchKernelGGL(k1c_max, dim3(1), dim3(256), 0, stream, ws + WS_AS, ws + WS_MAXS);
  hipLaunchKernelGGL(k2a_attn, dim3(256), dim3(256), 0, stream, x, ws + WS_H, ws + WS_AS,
                     ws + WS_AD, ws + WS_MAXS, gat_b, ws + WS_X1);
  hipLaunchKernelGGL(k2b_x1rest, dim3(3000), dim3(256), 0, stream, x, ws + WS_H, gat_b,
                     ws + WS_X1);
  hipLaunchKernelGGL(k3_conv, dim3(16, 16), dim3(320), 0, stream, ws + WS_X1, ws + WS_W2T,
                     ws, ws + WS_Y3P);
  hipLaunchKernelGGL(k4_proj, dim3(16), dim3(256), 0, stream, ws + WS_Y3P, ws, projc_w,
                     projc_b, ws + WS_Y5);
  hipLaunchKernelGGL(k5_fc1, dim3(8, 2), dim3(256), 0, stream, ws + WS_Y5, W1, b1,
                     ws + WS_Z, ws + WS_G);
  hipLaunchKernelGGL(k6_fc2, dim3(8, 2), dim3(256), 0, stream, ws + WS_G, ws + WS_Z, W2, b2,
                     ws + WS_Z2);
  hipLaunchKernelGGL(k7_ln, dim3(16), dim3(256), 0, stream, ws + WS_Z2, ln_g, ln_b, out);
}

// Round 2
// 417.180 us; speedup vs baseline: 1.4212x; 1.4212x over previous
//
#include <hip/hip_runtime.h>
#include <math.h>

// ---------------- workspace layout (float offsets) ----------------
// persistent region
#define WS_X1    0                    // 16384*200
#define WS_WPAD  3276800              // 200*256
#define WS_W2T   3328000              // 1024*1600  [n][c*40+o]
#define WS_AS    4966400              // 1024
#define WS_AD    4967424              // 1024
#define WS_MAXS  4968448              // 16
#define WS_WEFF  4968464              // 40*30
#define WS_S1    4969664              // 40
#define WS_SH1   4969704              // 40
#define WS_S2    4969744              // 40
#define WS_SH2   4969784              // 40
#define WS_H     4970496              // 16384*256 (h; region reused after k2b)
// overlays inside WS_H region (h is dead after k2b)
#define WS_Y3P   WS_H                 // 16*32*1400
#define WS_Y4    (WS_H + 716800)      // 16*1400
#define WS_Y5    (WS_H + 739200)      // 16*1400
#define WS_Z     (WS_H + 761600)      // 16*1024
#define WS_G     (WS_H + 777984)      // 16*1024
#define WS_ZP    (WS_H + 794368)      // 7*16*1024
#define WS_Z2P   (WS_H + 909056)      // 8*16*1024
// total: WS_H + 4194304 = 9,164,800 floats = 36.7 MB (< proven ws_size)

// ---------------- k0: small-parameter prep ----------------
__global__ void k0_prep(const float* __restrict__ gat_W,
                        const float* __restrict__ conv1_w, const float* __restrict__ conv1_b,
                        const float* __restrict__ bn1_g, const float* __restrict__ bn1_b,
                        const float* __restrict__ bn1_m, const float* __restrict__ bn1_v,
                        const float* __restrict__ conv2_b,
                        const float* __restrict__ bn2_g, const float* __restrict__ bn2_b,
                        const float* __restrict__ bn2_m, const float* __restrict__ bn2_v,
                        float* __restrict__ ws) {
  int t = threadIdx.x;
  float* wpad = ws + WS_WPAD;
  for (int i = t; i < 200 * 256; i += 256) {
    int k = i >> 8, c = i & 255;
    wpad[i] = (c < 200) ? gat_W[k * 200 + c] : 0.f;
  }
  if (t < 40) {
    float* weff = ws + WS_WEFF;
    for (int j = 0; j < 30; ++j) {
      float s = 0.f;
      for (int tt = 0; tt < 5; ++tt) {
        int k = j - tt;
        if (k >= 0 && k < 26) s += conv1_w[t * 26 + k];
      }
      weff[t * 30 + j] = s * 0.2f;
    }
    float s1 = bn1_g[t] * rsqrtf(bn1_v[t] + 1e-5f);
    ws[WS_S1 + t] = s1;
    ws[WS_SH1 + t] = bn1_b[t] + (conv1_b[t] - bn1_m[t]) * s1;
    float s2 = bn2_g[t] * rsqrtf(bn2_v[t] + 1e-5f);
    ws[WS_S2 + t] = s2;
    ws[WS_SH2 + t] = bn2_b[t] + (conv2_b[t] - bn2_m[t]) * s2;
  }
}

// ---------------- k0b: gather-transpose conv2_w (o,c,n) -> w2t[n][c*40+o] ----------------
__global__ __launch_bounds__(256) void k0b_w2t(const float* __restrict__ w2,
                                               float* __restrict__ w2t) {
  int idx = blockIdx.x * 256 + threadIdx.x;  // < 1024*1600
  int n = idx / 1600, j = idx % 1600;
  int c = j / 40, o = j % 40;
  w2t[idx] = w2[(o * 40 + c) * 1024 + n];
}

// ---------------- k1: h = x(16384x200) @ wpad(200x256), h stride 256 ----------------
__global__ __launch_bounds__(256) void k1_gemm_h(const float* __restrict__ x,
                                                 const float* __restrict__ wpad,
                                                 float* __restrict__ h) {
  __shared__ __align__(16) float As[8][64];
  __shared__ __align__(16) float Bs[8][64];
  int t = threadIdx.x;
  int tm = t & 15, tn = t >> 4;
  int row0 = blockIdx.x * 64;
  int col0 = blockIdx.y * 64;
  float acc[4][4] = {};
  for (int k0 = 0; k0 < 200; k0 += 8) {
    for (int i = t; i < 512; i += 256) {
      int m = i >> 3, k = i & 7;
      As[k][m] = x[(row0 + m) * 200 + k0 + k];
    }
    for (int i = t; i < 512; i += 256) {
      int k = i >> 6, n = i & 63;
      Bs[k][n] = wpad[(k0 + k) * 256 + col0 + n];
    }
    __syncthreads();
#pragma unroll
    for (int k = 0; k < 8; ++k) {
      float4 a = *(const float4*)&As[k][tm * 4];
      float4 bq = *(const float4*)&Bs[k][tn * 4];
      float av[4] = {a.x, a.y, a.z, a.w};
      float bv[4] = {bq.x, bq.y, bq.z, bq.w};
#pragma unroll
      for (int i = 0; i < 4; ++i)
#pragma unroll
        for (int j = 0; j < 4; ++j) acc[i][j] += av[i] * bv[j];
    }
    __syncthreads();
  }
#pragma unroll
  for (int i = 0; i < 4; ++i)
#pragma unroll
    for (int j = 0; j < 4; ++j)
      h[(row0 + tm * 4 + i) * 256 + col0 + tn * 4 + j] = acc[i][j];
}

// ---------------- k1b: attention scores ----------------
__global__ void k1b_scores(const float* __restrict__ h, const float* __restrict__ att_src,
                           const float* __restrict__ att_dst, float* __restrict__ as_,
                           float* __restrict__ ad_) {
  int r = blockIdx.x * 256 + threadIdx.x;  // < 1024
  const float* hr = h + r * 256;
  float s = 0.f, d = 0.f;
  for (int f = 0; f < 200; ++f) {
    float v = hr[f];
    s += v * att_src[f];
    d += v * att_dst[f];
  }
  as_[r] = s;
  ad_[r] = d;
}

// ---------------- k1c: max over a_s ----------------
__global__ void k1c_max(const float* __restrict__ as_, float* __restrict__ maxs) {
  __shared__ float rb[256];
  int t = threadIdx.x;
  float m = -1e30f;
  for (int j = t; j < 1024; j += 256) m = fmaxf(m, as_[j]);
  rb[t] = m;
  __syncthreads();
  for (int s = 128; s > 0; s >>= 1) {
    if (t < s) rb[t] = fmaxf(rb[t], rb[t + s]);
    __syncthreads();
  }
  if (t == 0) maxs[0] = rb[0];
}

// ---------------- k2a: dense attention graph 0 ----------------
__global__ __launch_bounds__(256) void k2a_attn(const float* __restrict__ x,
                                                const float* __restrict__ h,
                                                const float* __restrict__ as_,
                                                const float* __restrict__ ad_,
                                                const float* __restrict__ maxs_p,
                                                const float* __restrict__ gat_b,
                                                float* __restrict__ x1) {
  __shared__ float pbuf[4][1024];
  __shared__ float rb[256];
  __shared__ float dsh[4];
  int t = threadIdx.x;
  int i0 = blockIdx.x * 4;
  float maxs = maxs_p[0];
  float M[4], ad[4], dsum[4] = {0, 0, 0, 0};
#pragma unroll
  for (int ii = 0; ii < 4; ++ii) {
    ad[ii] = ad_[i0 + ii];
    float v = maxs + ad[ii];
    M[ii] = v >= 0.f ? v : 0.2f * v;
  }
  for (int j = t; j < 1024; j += 256) {
    float asj = as_[j];
#pragma unroll
    for (int ii = 0; ii < 4; ++ii) {
      float v = asj + ad[ii];
      float l = v >= 0.f ? v : 0.2f * v;
      float p = __expf(l - M[ii]);
      pbuf[ii][j] = p;
      dsum[ii] += p;
    }
  }
  __syncthreads();
  for (int ii = 0; ii < 4; ++ii) {
    rb[t] = dsum[ii];
    __syncthreads();
    for (int s = 128; s > 0; s >>= 1) {
      if (t < s) rb[t] += rb[t + s];
      __syncthreads();
    }
    if (t == 0) dsh[ii] = rb[0];
    __syncthreads();
  }
  if (t < 200) {
    float acc[4] = {0, 0, 0, 0};
    for (int j = 0; j < 1024; ++j) {
      float hv = h[j * 256 + t];
#pragma unroll
      for (int ii = 0; ii < 4; ++ii) acc[ii] += pbuf[ii][j] * hv;
    }
    float gb = gat_b[t];
#pragma unroll
    for (int ii = 0; ii < 4; ++ii) {
      int i = i0 + ii;
      x1[i * 200 + t] = x[i * 200 + t] + acc[ii] / dsh[ii] + gb;
    }
  }
}

// ---------------- k2b: x1 rows [1024,16384) ----------------
__global__ void k2b_x1rest(const float* __restrict__ x, const float* __restrict__ h,
                           const float* __restrict__ gat_b, float* __restrict__ x1) {
  int id = blockIdx.x * 256 + threadIdx.x;
  int r = 1024 + id / 50;
  int q = (id % 50) * 4;
  float4 xv = *(const float4*)(x + r * 200 + q);
  float4 hv = *(const float4*)(h + r * 256 + q);
  float4 gb = *(const float4*)(gat_b + q);
  float4 o;
  o.x = xv.x + hv.x + gb.x;
  o.y = xv.y + hv.y + gb.y;
  o.z = xv.z + hv.z + gb.z;
  o.w = xv.w + hv.w + gb.w;
  *(float4*)(x1 + r * 200 + q) = o;
}

// ---------------- k3: fused conv1+bn1+elu+conv2, 4 nodes/iter, 2 blocks/CU ----------------
// grid (16 b, 32 nt), block 320. Each block handles 32 nodes in 8 iters.
__global__ __launch_bounds__(320, 2) void k3_conv(const float* __restrict__ x1,
                                                  const float* __restrict__ w2t,
                                                  const float* __restrict__ ws,
                                                  float* __restrict__ y3p) {
  __shared__ __align__(16) float xbp[1280];    // 4 nodes x 40 blocks x (5+3 pad)
  __shared__ __align__(16) float w2s[6400];    // 4 nodes x [c*40+o]
  __shared__ __align__(16) float tmpP[8960];   // 4 nodes x 40c x 7wg x (5+3 pad)
  int t = threadIdx.x;
  int b = blockIdx.x, nt = blockIdx.y;
  // conv1 mapping: (c1, wg), loops all 4 nodes
  int c1 = t / 7, wg = t % 7;
  // conv2 mapping: (nn2, cg, pg), one node per iter
  int nn2 = t / 70, rr = t % 70, cg = rr / 7, pg = rr % 7;
  float wr[30];
  float s1c = 0.f, sh1c = 0.f;
  if (t < 280) {
    const float* weff = ws + WS_WEFF + c1 * 30;
#pragma unroll
    for (int j = 0; j < 30; ++j) wr[j] = weff[j];
    s1c = ws[WS_S1 + c1];
    sh1c = ws[WS_SH1 + c1];
  }
  float acc[4][5] = {};
  for (int it = 0; it < 8; ++it) {
    int n0 = nt * 32 + it * 4;
    // stage w2: contiguous 1600-float4 copy (4 node rows)
    const float4* wsrc = (const float4*)(w2t + n0 * 1600);
#pragma unroll
    for (int s = 0; s < 5; ++s) ((float4*)w2s)[t + s * 320] = wsrc[t + s * 320];
    // stage x into padded 5-blocks
    if (t < 200) {
      int nn = t / 50, q = t % 50;
      float4 v = ((const float4*)(x1 + (b * 1024 + n0 + nn) * 200))[q];
      float vv[4] = {v.x, v.y, v.z, v.w};
      int j0 = q * 4;
#pragma unroll
      for (int m = 0; m < 4; ++m) {
        int j = j0 + m;
        xbp[nn * 320 + (j / 5) * 8 + (j % 5)] = vv[m];
      }
    }
    __syncthreads();
    // conv1 + bn1 + elu -> tmpP
    if (t < 280) {
#pragma unroll
      for (int nn = 0; nn < 4; ++nn) {
        float xq[10][5];
        int base = nn * 320 + wg * 40;
#pragma unroll
        for (int pi = 0; pi < 10; ++pi) {
          float4 v = *(const float4*)&xbp[base + pi * 8];
          xq[pi][0] = v.x; xq[pi][1] = v.y; xq[pi][2] = v.z; xq[pi][3] = v.w;
          xq[pi][4] = xbp[base + pi * 8 + 4];
        }
        float e[5];
#pragma unroll
        for (int u = 0; u < 5; ++u) {
          float s = 0.f;
#pragma unroll
          for (int m = 0; m < 6; ++m)
#pragma unroll
            for (int r = 0; r < 5; ++r) s += xq[u + m][r] * wr[m * 5 + r];
          float v = s * s1c + sh1c;
          e[u] = v > 0.f ? v : __expf(v) - 1.f;
        }
        float* tp = &tmpP[((nn * 40 + c1) * 7 + wg) * 8];
        *(float4*)tp = make_float4(e[0], e[1], e[2], e[3]);
        tp[4] = e[4];
      }
    }
    __syncthreads();
    // conv2 accumulate
    if (t < 280) {
      const float* tb = &tmpP[nn2 * 2240 + pg * 8];
      const float* wb = &w2s[nn2 * 1600 + cg * 4];
#pragma unroll 4
      for (int cc = 0; cc < 40; ++cc) {
        float4 tv = *(const float4*)&tb[cc * 56];
        float t4 = tb[cc * 56 + 4];
        float4 wv = *(const float4*)&wb[cc * 40];
        acc[0][0] += tv.x * wv.x; acc[0][1] += tv.y * wv.x; acc[0][2] += tv.z * wv.x;
        acc[0][3] += tv.w * wv.x; acc[0][4] += t4 * wv.x;
        acc[1][0] += tv.x * wv.y; acc[1][1] += tv.y * wv.y; acc[1][2] += tv.z * wv.y;
        acc[1][3] += tv.w * wv.y; acc[1][4] += t4 * wv.y;
        acc[2][0] += tv.x * wv.z; acc[2][1] += tv.y * wv.z; acc[2][2] += tv.z * wv.z;
        acc[2][3] += tv.w * wv.z; acc[2][4] += t4 * wv.z;
        acc[3][0] += tv.x * wv.w; acc[3][1] += tv.y * wv.w; acc[3][2] += tv.z * wv.w;
        acc[3][3] += tv.w * wv.w; acc[3][4] += t4 * wv.w;
      }
    }
    __syncthreads();
  }
  // in-block reduction over the 4 nn2 sub-partials -> one partial per (b,nt)
  if (t < 280) {
#pragma unroll
    for (int oi = 0; oi < 4; ++oi)
#pragma unroll
      for (int u = 0; u < 5; ++u)
        tmpP[nn2 * 1400 + (cg * 4 + oi) * 35 + pg * 5 + u] = acc[oi][u];
  }
  __syncthreads();
  float* dst = y3p + (b * 32 + nt) * 1400;
  for (int idx = t; idx < 1400; idx += 320)
    dst[idx] = tmpP[idx] + tmpP[1400 + idx] + tmpP[2800 + idx] + tmpP[4200 + idx];
}

// ---------------- k4a: reduce 32 partials + bn2 + elu -> y4 ----------------
__global__ __launch_bounds__(256) void k4a_red(const float* __restrict__ y3p,
                                               const float* __restrict__ ws,
                                               float* __restrict__ y4) {
  int t = threadIdx.x;
  if (t >= 200) return;
  int b = blockIdx.x;
  int idx = blockIdx.y * 200 + t;  // < 1400
  float s = 0.f;
  for (int q = 0; q < 32; ++q) s += y3p[(b * 32 + q) * 1400 + idx];
  int o = idx / 35;
  float v = s * ws[WS_S2 + o] + ws[WS_SH2 + o];
  y4[b * 1400 + idx] = v > 0.f ? v : __expf(v) - 1.f;
}

// ---------------- k4b: projc + rearrange -> y5 ----------------
__global__ __launch_bounds__(256) void k4b_proj(const float* __restrict__ y4,
                                                const float* __restrict__ projc_w,
                                                const float* __restrict__ projc_b,
                                                float* __restrict__ y5) {
  __shared__ __align__(16) float tls[1400];
  int t = threadIdx.x, b = blockIdx.x;
  for (int i = t; i < 350; i += 256)
    ((float4*)tls)[i] = ((const float4*)(y4 + b * 1400))[i];
  __syncthreads();
  for (int idx = t; idx < 1400; idx += 256) {
    int p = idx / 40, e = idx % 40;
    float acc = projc_b[e];
    for (int o = 0; o < 40; ++o) acc += tls[o * 35 + p] * projc_w[e * 40 + o];
    y5[b * 1400 + idx] = acc;
  }
}

// ---------------- k5: split-K FC1 partials ----------------
__global__ __launch_bounds__(256) void k5_fc1(const float* __restrict__ y5,
                                              const float* __restrict__ W1,
                                              float* __restrict__ zp) {
  __shared__ __align__(16) float yls[8 * 200];
  int t = threadIdx.x;
  int cb = blockIdx.x, bh = blockIdx.y, kc = blockIdx.z;  // (8,2,7)
  for (int i = t; i < 400; i += 256) {
    int r = i / 50, q = i % 50;
    ((float4*)yls)[r * 50 + q] = *(const float4*)(y5 + (bh * 8 + r) * 1400 + kc * 200 + q * 4);
  }
  __syncthreads();
  int nq = t & 31, bl = t >> 5;
  int n = cb * 128 + nq * 4;
  int b = bh * 8 + bl;
  float4 acc = make_float4(0.f, 0.f, 0.f, 0.f);
  const float* yrow = yls + bl * 200;
  for (int k = 0; k < 200; ++k) {
    float yv = yrow[k];
    float4 w = *(const float4*)(W1 + (kc * 200 + k) * 1024 + n);
    acc.x += yv * w.x; acc.y += yv * w.y; acc.z += yv * w.z; acc.w += yv * w.w;
  }
  *(float4*)(zp + (kc * 16 + b) * 1024 + n) = acc;
}

// ---------------- k5b: reduce FC1 partials + bias; z, gelu(z) ----------------
__global__ __launch_bounds__(256) void k5b_red(const float* __restrict__ zp,
                                               const float* __restrict__ b1,
                                               float* __restrict__ z, float* __restrict__ g) {
  int gid = blockIdx.x * 256 + threadIdx.x;  // < 16384
  int b = gid >> 10, n = gid & 1023;
  float s = b1[n];
#pragma unroll
  for (int kc = 0; kc < 7; ++kc) s += zp[(kc * 16 + b) * 1024 + n];
  z[gid] = s;
  g[gid] = 0.5f * s * (1.f + erff(s * 0.70710678f));
}

// ---------------- k6: split-K FC2 partials ----------------
__global__ __launch_bounds__(256) void k6_fc2(const float* __restrict__ g,
                                              const float* __restrict__ W2,
                                              float* __restrict__ z2p) {
  __shared__ __align__(16) float gls[8 * 128];
  int t = threadIdx.x;
  int cb = blockIdx.x, bh = blockIdx.y, kc = blockIdx.z;  // (8,2,8)
  for (int i = t; i < 256; i += 256) {
    int r = i / 32, q = i % 32;
    ((float4*)gls)[r * 32 + q] = *(const float4*)(g + (bh * 8 + r) * 1024 + kc * 128 + q * 4);
  }
  __syncthreads();
  int nq = t & 31, bl = t >> 5;
  int n = cb * 128 + nq * 4;
  int b = bh * 8 + bl;
  float4 acc = make_float4(0.f, 0.f, 0.f, 0.f);
  const float* grow = gls + bl * 128;
  for (int k = 0; k < 128; ++k) {
    float gv = grow[k];
    float4 w = *(const float4*)(W2 + (kc * 128 + k) * 1024 + n);
    acc.x += gv * w.x; acc.y += gv * w.y; acc.z += gv * w.z; acc.w += gv * w.w;
  }
  *(float4*)(z2p + (kc * 16 + b) * 1024 + n) = acc;
}

// ---------------- k7: reduce FC2 partials + residual + LayerNorm ----------------
__global__ __launch_bounds__(256) void k7_ln(const float* __restrict__ z,
                                             const float* __restrict__ z2p,
                                             const float* __restrict__ b2,
                                             const float* __restrict__ ln_g,
                                             const float* __restrict__ ln_b,
                                             float* __restrict__ out) {
  __shared__ float r1[256], r2[256];
  int t = threadIdx.x, b = blockIdx.x;
  float4 v = *(const float4*)(z + b * 1024 + t * 4);
  float4 bb2 = *(const float4*)(b2 + t * 4);
  v.x += bb2.x; v.y += bb2.y; v.z += bb2.z; v.w += bb2.w;
#pragma unroll
  for (int kc = 0; kc < 8; ++kc) {
    float4 p = *(const float4*)(z2p + (kc * 16 + b) * 1024 + t * 4);
    v.x += p.x; v.y += p.y; v.z += p.z; v.w += p.w;
  }
  r1[t] = v.x + v.y + v.z + v.w;
  r2[t] = v.x * v.x + v.y * v.y + v.z * v.z + v.w * v.w;
  __syncthreads();
  for (int s = 128; s > 0; s >>= 1) {
    if (t < s) {
      r1[t] += r1[t + s];
      r2[t] += r2[t + s];
    }
    __syncthreads();
  }
  float mu = r1[0] * (1.f / 1024.f);
  float var = r2[0] * (1.f / 1024.f) - mu * mu;
  float rstd = rsqrtf(var + 1e-5f);
  float4 gg = *(const float4*)(ln_g + t * 4);
  float4 bb = *(const float4*)(ln_b + t * 4);
  float4 o;
  o.x = (v.x - mu) * rstd * gg.x + bb.x;
  o.y = (v.y - mu) * rstd * gg.y + bb.y;
  o.z = (v.z - mu) * rstd * gg.z + bb.z;
  o.w = (v.w - mu) * rstd * gg.w + bb.w;
  *(float4*)(out + b * 1024 + t * 4) = o;
}

extern "C" void kernel_launch(void* const* d_in, const int* in_sizes, int n_in,
                              void* d_out, int out_size, void* d_ws, size_t ws_size,
                              hipStream_t stream) {
  (void)in_sizes; (void)n_in; (void)out_size; (void)ws_size;
  const float* x       = (const float*)d_in[0];
  const float* gat_W   = (const float*)d_in[1];
  const float* att_src = (const float*)d_in[2];
  const float* att_dst = (const float*)d_in[3];
  const float* gat_b   = (const float*)d_in[4];
  const float* conv1_w = (const float*)d_in[5];
  const float* conv1_b = (const float*)d_in[6];
  const float* bn1_g   = (const float*)d_in[7];
  const float* bn1_b   = (const float*)d_in[8];
  const float* bn1_m   = (const float*)d_in[9];
  const float* bn1_v   = (const float*)d_in[10];
  const float* conv2_w = (const float*)d_in[11];
  const float* projc_w = (const float*)d_in[17];
  const float* projc_b = (const float*)d_in[18];
  const float* W1      = (const float*)d_in[19];
  const float* b1      = (const float*)d_in[20];
  const float* W2      = (const float*)d_in[21];
  const float* b2      = (const float*)d_in[22];
  const float* ln_g    = (const float*)d_in[23];
  const float* ln_b    = (const float*)d_in[24];
  float* ws  = (float*)d_ws;
  float* out = (float*)d_out;

  hipLaunchKernelGGL(k0_prep, dim3(1), dim3(256), 0, stream, gat_W, conv1_w, (const float*)d_in[6],
                     bn1_g, bn1_b, bn1_m, bn1_v, (const float*)d_in[12], (const float*)d_in[13],
                     (const float*)d_in[14], (const float*)d_in[15], (const float*)d_in[16], ws);
  hipLaunchKernelGGL(k0b_w2t, dim3(6400), dim3(256), 0, stream, conv2_w, ws + WS_W2T);
  hipLaunchKernelGGL(k1_gemm_h, dim3(256, 4), dim3(256), 0, stream, x, ws + WS_WPAD, ws + WS_H);
  hipLaunchKernelGGL(k1b_scores, dim3(4), dim3(256), 0, stream, ws + WS_H, att_src, att_dst,
                     ws + WS_AS, ws + WS_AD);
  hipLaunchKernelGGL(k1c_max, dim3(1), dim3(256), 0, stream, ws + WS_AS, ws + WS_MAXS);
  hipLaunchKernelGGL(k2a_attn, dim3(256), dim3(256), 0, stream, x, ws + WS_H, ws + WS_AS,
                     ws + WS_AD, ws + WS_MAXS, gat_b, ws + WS_X1);
  hipLaunchKernelGGL(k2b_x1rest, dim3(3000), dim3(256), 0, stream, x, ws + WS_H, gat_b,
                     ws + WS_X1);
  hipLaunchKernelGGL(k3_conv, dim3(16, 32), dim3(320), 0, stream, ws + WS_X1, ws + WS_W2T,
                     ws, ws + WS_Y3P);
  hipLaunchKernelGGL(k4a_red, dim3(16, 7), dim3(256), 0, stream, ws + WS_Y3P, ws, ws + WS_Y4);
  hipLaunchKernelGGL(k4b_proj, dim3(16), dim3(256), 0, stream, ws + WS_Y4, projc_w, projc_b,
                     ws + WS_Y5);
  hipLaunchKernelGGL(k5_fc1, dim3(8, 2, 7), dim3(256), 0, stream, ws + WS_Y5, W1, ws + WS_ZP);
  hipLaunchKernelGGL(k5b_red, dim3(64), dim3(256), 0, stream, ws + WS_ZP, b1, ws + WS_Z,
                     ws + WS_G);
  hipLaunchKernelGGL(k6_fc2, dim3(8, 2, 8), dim3(256), 0, stream, ws + WS_G, W2, ws + WS_Z2P);
  hipLaunchKernelGGL(k7_ln, dim3(16), dim3(256), 0, stream, ws + WS_Z, ws + WS_Z2P, b2,
                     ln_g, ln_b, out);
}

// Round 3
// 378.130 us; speedup vs baseline: 1.5680x; 1.1033x over previous
//
#include <hip/hip_runtime.h>
#include <math.h>

// ---------------- workspace layout (float offsets) ----------------
#define WS_X1    0                    // 16384*200
#define WS_WPAD  3276800              // 200*256
#define WS_W2T   3328000              // 1024*1600  [n][c*40+o]
#define WS_AS    4966400              // 1024
#define WS_AD    4967424              // 1024
#define WS_MAXS  4968448              // 16
#define WS_WEFF  4968464              // 40*30
#define WS_S1    4969664              // 40
#define WS_SH1   4969704              // 40
#define WS_S2    4969744              // 40
#define WS_SH2   4969784              // 40
#define WS_H     4970496              // 1024*256 (only graph-0 rows needed)
#define WS_P     5232640              // 1024*1024 normalized softmax P
#define WS_AP    6281216              // 4*1024*256 attention split-K partials
#define WS_Y3P   7329792              // 16*32*1400
#define WS_Y4    8046592              // (unused spare)
#define WS_Y5    8068992              // 16*1400
#define WS_Z     8091392              // 16*1024
#define WS_G     8107776              // 16*1024
#define WS_ZP    8124160              // 7*16*1024
#define WS_Z2P   8238848              // 8*16*1024
// end 8,369,920 floats = 33.5 MB (< proven ws_size)

// ---------------- k0: parameter prep (201 blocks) ----------------
__global__ __launch_bounds__(256) void k0_prep(const float* __restrict__ gat_W,
                        const float* __restrict__ conv1_w, const float* __restrict__ conv1_b,
                        const float* __restrict__ bn1_g, const float* __restrict__ bn1_b,
                        const float* __restrict__ bn1_m, const float* __restrict__ bn1_v,
                        const float* __restrict__ conv2_b,
                        const float* __restrict__ bn2_g, const float* __restrict__ bn2_b,
                        const float* __restrict__ bn2_m, const float* __restrict__ bn2_v,
                        float* __restrict__ ws) {
  int bx = blockIdx.x, t = threadIdx.x;
  if (bx < 200) {
    ws[WS_WPAD + bx * 256 + t] = (t < 200) ? gat_W[bx * 200 + t] : 0.f;
    return;
  }
  if (t < 40) {
    float* weff = ws + WS_WEFF;
    for (int j = 0; j < 30; ++j) {
      float s = 0.f;
      for (int tt = 0; tt < 5; ++tt) {
        int k = j - tt;
        if (k >= 0 && k < 26) s += conv1_w[t * 26 + k];
      }
      weff[t * 30 + j] = s * 0.2f;
    }
    float s1 = bn1_g[t] * rsqrtf(bn1_v[t] + 1e-5f);
    ws[WS_S1 + t] = s1;
    ws[WS_SH1 + t] = bn1_b[t] + (conv1_b[t] - bn1_m[t]) * s1;
    float s2 = bn2_g[t] * rsqrtf(bn2_v[t] + 1e-5f);
    ws[WS_S2 + t] = s2;
    ws[WS_SH2 + t] = bn2_b[t] + (conv2_b[t] - bn2_m[t]) * s2;
  }
}

// ---------------- k0b: gather-transpose conv2_w (o,c,n) -> w2t[n][c*40+o] ----------------
__global__ __launch_bounds__(256) void k0b_w2t(const float* __restrict__ w2,
                                               float* __restrict__ w2t) {
  int idx = blockIdx.x * 256 + threadIdx.x;  // < 1024*1600
  int n = idx / 1600, j = idx % 1600;
  int c = j / 40, o = j % 40;
  w2t[idx] = w2[(o * 40 + c) * 1024 + n];
}

// ---------------- k1: h = x @ wpad; rows>=1024 fused into x1 ----------------
__global__ __launch_bounds__(256) void k1_gemm_h(const float* __restrict__ x,
                                                 const float* __restrict__ wpad,
                                                 const float* __restrict__ gat_b,
                                                 float* __restrict__ h,
                                                 float* __restrict__ x1) {
  __shared__ __align__(16) float As[8][64];
  __shared__ __align__(16) float Bs[8][64];
  int t = threadIdx.x;
  int tm = t & 15, tn = t >> 4;
  int row0 = blockIdx.x * 64;
  int col0 = blockIdx.y * 64;
  float acc[4][4] = {};
  for (int k0 = 0; k0 < 200; k0 += 8) {
    for (int i = t; i < 512; i += 256) {
      int m = i >> 3, k = i & 7;
      As[k][m] = x[(row0 + m) * 200 + k0 + k];
    }
    for (int i = t; i < 512; i += 256) {
      int k = i >> 6, n = i & 63;
      Bs[k][n] = wpad[(k0 + k) * 256 + col0 + n];
    }
    __syncthreads();
#pragma unroll
    for (int k = 0; k < 8; ++k) {
      float4 a = *(const float4*)&As[k][tm * 4];
      float4 bq = *(const float4*)&Bs[k][tn * 4];
      float av[4] = {a.x, a.y, a.z, a.w};
      float bv[4] = {bq.x, bq.y, bq.z, bq.w};
#pragma unroll
      for (int i = 0; i < 4; ++i)
#pragma unroll
        for (int j = 0; j < 4; ++j) acc[i][j] += av[i] * bv[j];
    }
    __syncthreads();
  }
  if (row0 < 1024) {
#pragma unroll
    for (int i = 0; i < 4; ++i)
#pragma unroll
      for (int j = 0; j < 4; ++j)
        h[(row0 + tm * 4 + i) * 256 + col0 + tn * 4 + j] = acc[i][j];
  } else {
    int col = col0 + tn * 4;
    if (col < 200) {
      float4 gb = *(const float4*)(gat_b + col);
#pragma unroll
      for (int i = 0; i < 4; ++i) {
        int row = row0 + tm * 4 + i;
        float4 xv = *(const float4*)(x + row * 200 + col);
        float4 o;
        o.x = xv.x + acc[i][0] + gb.x;
        o.y = xv.y + acc[i][1] + gb.y;
        o.z = xv.z + acc[i][2] + gb.z;
        o.w = xv.w + acc[i][3] + gb.w;
        *(float4*)(x1 + row * 200 + col) = o;
      }
    }
  }
}

// ---------------- k1b: attention scores ----------------
__global__ void k1b_scores(const float* __restrict__ h, const float* __restrict__ att_src,
                           const float* __restrict__ att_dst, float* __restrict__ as_,
                           float* __restrict__ ad_) {
  int r = blockIdx.x * 256 + threadIdx.x;  // < 1024
  const float* hr = h + r * 256;
  float s = 0.f, d = 0.f;
  for (int f = 0; f < 200; ++f) {
    float v = hr[f];
    s += v * att_src[f];
    d += v * att_dst[f];
  }
  as_[r] = s;
  ad_[r] = d;
}

// ---------------- k1c: max over a_s ----------------
__global__ void k1c_max(const float* __restrict__ as_, float* __restrict__ maxs) {
  __shared__ float rb[256];
  int t = threadIdx.x;
  float m = -1e30f;
  for (int j = t; j < 1024; j += 256) m = fmaxf(m, as_[j]);
  rb[t] = m;
  __syncthreads();
  for (int s = 128; s > 0; s >>= 1) {
    if (t < s) rb[t] = fmaxf(rb[t], rb[t + s]);
    __syncthreads();
  }
  if (t == 0) maxs[0] = rb[0];
}

// ---------------- kP: normalized softmax P[i][j] (denom folded in) ----------------
__global__ __launch_bounds__(256) void kP(const float* __restrict__ as_,
                                          const float* __restrict__ ad_,
                                          const float* __restrict__ maxs_p,
                                          float* __restrict__ P) {
  __shared__ float rb[256];
  int t = threadIdx.x, i = blockIdx.x;
  float ad = ad_[i];
  float mv = maxs_p[0] + ad;
  float M = mv >= 0.f ? mv : 0.2f * mv;
  float p[4];
  float s = 0.f;
#pragma unroll
  for (int q = 0; q < 4; ++q) {
    float v = as_[q * 256 + t] + ad;
    float l = v >= 0.f ? v : 0.2f * v;
    p[q] = __expf(l - M);
    s += p[q];
  }
  rb[t] = s;
  __syncthreads();
  for (int st = 128; st > 0; st >>= 1) {
    if (t < st) rb[t] += rb[t + st];
    __syncthreads();
  }
  float inv = 1.f / rb[0];
#pragma unroll
  for (int q = 0; q < 4; ++q) P[i * 1024 + q * 256 + t] = p[q] * inv;
}

// ---------------- kAttn: split-K GEMM out0 = P @ h ----------------
__global__ __launch_bounds__(256) void kAttn(const float* __restrict__ P,
                                             const float* __restrict__ h,
                                             float* __restrict__ ap) {
  __shared__ __align__(16) float As[8][64];
  __shared__ __align__(16) float Bs[8][64];
  int t = threadIdx.x;
  int tm = t & 15, tn = t >> 4;
  int i0 = blockIdx.x * 64, f0 = blockIdx.y * 64, j0 = blockIdx.z * 256;
  float acc[4][4] = {};
  for (int k0 = 0; k0 < 256; k0 += 8) {
    for (int i = t; i < 512; i += 256) {
      int m = i >> 3, k = i & 7;
      As[k][m] = P[(i0 + m) * 1024 + j0 + k0 + k];
    }
    for (int i = t; i < 512; i += 256) {
      int k = i >> 6, n = i & 63;
      Bs[k][n] = h[(j0 + k0 + k) * 256 + f0 + n];
    }
    __syncthreads();
#pragma unroll
    for (int k = 0; k < 8; ++k) {
      float4 a = *(const float4*)&As[k][tm * 4];
      float4 bq = *(const float4*)&Bs[k][tn * 4];
      float av[4] = {a.x, a.y, a.z, a.w};
      float bv[4] = {bq.x, bq.y, bq.z, bq.w};
#pragma unroll
      for (int i = 0; i < 4; ++i)
#pragma unroll
        for (int j = 0; j < 4; ++j) acc[i][j] += av[i] * bv[j];
    }
    __syncthreads();
  }
#pragma unroll
  for (int i = 0; i < 4; ++i) {
    int r = i0 + tm * 4 + i;
    float4 v = make_float4(acc[i][0], acc[i][1], acc[i][2], acc[i][3]);
    *(float4*)&ap[(blockIdx.z * 1024 + r) * 256 + f0 + tn * 4] = v;
  }
}

// ---------------- kAttnRed: reduce partials + residual -> x1 rows [0,1024) ----------------
__global__ __launch_bounds__(256) void kAttnRed(const float* __restrict__ ap,
                                                const float* __restrict__ x,
                                                const float* __restrict__ gat_b,
                                                float* __restrict__ x1) {
  int t = threadIdx.x, r = blockIdx.x;
  if (t >= 200) return;
  float s = ap[r * 256 + t] + ap[(1024 + r) * 256 + t] + ap[(2048 + r) * 256 + t] +
            ap[(3072 + r) * 256 + t];
  x1[r * 200 + t] = x[r * 200 + t] + s + gat_b[t];
}

// ---------------- k3: fused conv1+bn1+elu+conv2, conflict-free tmp layout ----------------
// tmpP layout: addr(nn,c,wg) = nn*3364 + c*84 + wg*12 (+u), 5 valid of 12
__global__ __launch_bounds__(320, 2) void k3_conv(const float* __restrict__ x1,
                                                  const float* __restrict__ w2t,
                                                  const float* __restrict__ ws,
                                                  float* __restrict__ y3p) {
  __shared__ __align__(16) float xbp[1280];     // 4 nodes x 40 windows x 8
  __shared__ __align__(16) float tmpP[13456];   // 4 x 3364
  int t = threadIdx.x;
  int b = blockIdx.x, nt = blockIdx.y;
  int c1 = t / 7, wg = t % 7;
  int nn2 = t / 70, rr = t % 70, cg = rr / 7, pg = rr % 7;
  float wr[30];
  float s1c = 0.f, sh1c = 0.f;
  if (t < 280) {
    const float* weff = ws + WS_WEFF + c1 * 30;
#pragma unroll
    for (int j = 0; j < 30; ++j) wr[j] = weff[j];
    s1c = ws[WS_S1 + c1];
    sh1c = ws[WS_SH1 + c1];
  }
  float acc[4][5] = {};
  for (int it = 0; it < 8; ++it) {
    int n0 = nt * 32 + it * 4;
    if (t < 200) {
      int nn = t / 50, q = t % 50;
      float4 v = ((const float4*)(x1 + (b * 1024 + n0 + nn) * 200))[q];
      float vv[4] = {v.x, v.y, v.z, v.w};
      int j0 = q * 4;
#pragma unroll
      for (int m = 0; m < 4; ++m) {
        int j = j0 + m;
        xbp[nn * 320 + (j / 5) * 8 + (j % 5)] = vv[m];
      }
    }
    __syncthreads();
    if (t < 280) {
#pragma unroll
      for (int nn = 0; nn < 4; ++nn) {
        float xq[10][5];
        int base = nn * 320 + wg * 40;
#pragma unroll
        for (int pi = 0; pi < 10; ++pi) {
          float4 v = *(const float4*)&xbp[base + pi * 8];
          xq[pi][0] = v.x; xq[pi][1] = v.y; xq[pi][2] = v.z; xq[pi][3] = v.w;
          xq[pi][4] = xbp[base + pi * 8 + 4];
        }
        float e[5];
#pragma unroll
        for (int u = 0; u < 5; ++u) {
          float s = 0.f;
#pragma unroll
          for (int m = 0; m < 6; ++m)
#pragma unroll
            for (int r = 0; r < 5; ++r) s += xq[u + m][r] * wr[m * 5 + r];
          float v = s * s1c + sh1c;
          e[u] = v > 0.f ? v : __expf(v) - 1.f;
        }
        float* tp = &tmpP[nn * 3364 + c1 * 84 + wg * 12];
        *(float4*)tp = make_float4(e[0], e[1], e[2], e[3]);
        tp[4] = e[4];
      }
    }
    __syncthreads();
    if (t < 280) {
      const float* tb = &tmpP[nn2 * 3364 + pg * 12];
      const float* wrow = w2t + (n0 + nn2) * 1600 + cg * 4;
#pragma unroll 4
      for (int cc = 0; cc < 40; ++cc) {
        float4 tv = *(const float4*)&tb[cc * 84];
        float t4 = tb[cc * 84 + 4];
        float4 wv = *(const float4*)(wrow + cc * 40);
        acc[0][0] += tv.x * wv.x; acc[0][1] += tv.y * wv.x; acc[0][2] += tv.z * wv.x;
        acc[0][3] += tv.w * wv.x; acc[0][4] += t4 * wv.x;
        acc[1][0] += tv.x * wv.y; acc[1][1] += tv.y * wv.y; acc[1][2] += tv.z * wv.y;
        acc[1][3] += tv.w * wv.y; acc[1][4] += t4 * wv.y;
        acc[2][0] += tv.x * wv.z; acc[2][1] += tv.y * wv.z; acc[2][2] += tv.z * wv.z;
        acc[2][3] += tv.w * wv.z; acc[2][4] += t4 * wv.z;
        acc[3][0] += tv.x * wv.w; acc[3][1] += tv.y * wv.w; acc[3][2] += tv.z * wv.w;
        acc[3][3] += tv.w * wv.w; acc[3][4] += t4 * wv.w;
      }
    }
    __syncthreads();
  }
  if (t < 280) {
#pragma unroll
    for (int oi = 0; oi < 4; ++oi)
#pragma unroll
      for (int u = 0; u < 5; ++u)
        tmpP[nn2 * 1400 + (cg * 4 + oi) * 35 + pg * 5 + u] = acc[oi][u];
  }
  __syncthreads();
  float* dst = y3p + (b * 32 + nt) * 1400;
  for (int idx = t; idx < 1400; idx += 320)
    dst[idx] = tmpP[idx] + tmpP[1400 + idx] + tmpP[2800 + idx] + tmpP[4200 + idx];
}

// ---------------- k4: reduce partials + bn2 + elu + projc -> y5 ----------------
__global__ __launch_bounds__(256) void k4_projred(const float* __restrict__ y3p,
                                                  const float* __restrict__ ws,
                                                  const float* __restrict__ projc_w,
                                                  const float* __restrict__ projc_b,
                                                  float* __restrict__ y5) {
  __shared__ float tls[1400];
  int t = threadIdx.x, b = blockIdx.x;
  for (int idx = t; idx < 1400; idx += 256) {
    float s = 0.f;
    for (int q = 0; q < 32; ++q) s += y3p[(b * 32 + q) * 1400 + idx];
    int o = idx / 35;
    float v = s * ws[WS_S2 + o] + ws[WS_SH2 + o];
    tls[idx] = v > 0.f ? v : __expf(v) - 1.f;
  }
  __syncthreads();
  for (int idx = t; idx < 1400; idx += 256) {
    int p = idx / 40, e = idx % 40;
    float acc = projc_b[e];
    for (int o = 0; o < 40; ++o) acc += tls[o * 35 + p] * projc_w[e * 40 + o];
    y5[b * 1400 + idx] = acc;
  }
}

// ---------------- k5: split-K FC1 partials ----------------
__global__ __launch_bounds__(256) void k5_fc1(const float* __restrict__ y5,
                                              const float* __restrict__ W1,
                                              float* __restrict__ zp) {
  __shared__ __align__(16) float yls[8 * 200];
  int t = threadIdx.x;
  int cb = blockIdx.x, bh = blockIdx.y, kc = blockIdx.z;  // (8,2,7)
  for (int i = t; i < 400; i += 256) {
    int r = i / 50, q = i % 50;
    ((float4*)yls)[r * 50 + q] = *(const float4*)(y5 + (bh * 8 + r) * 1400 + kc * 200 + q * 4);
  }
  __syncthreads();
  int nq = t & 31, bl = t >> 5;
  int n = cb * 128 + nq * 4;
  int b = bh * 8 + bl;
  float4 acc = make_float4(0.f, 0.f, 0.f, 0.f);
  const float* yrow = yls + bl * 200;
  for (int k = 0; k < 200; ++k) {
    float yv = yrow[k];
    float4 w = *(const float4*)(W1 + (kc * 200 + k) * 1024 + n);
    acc.x += yv * w.x; acc.y += yv * w.y; acc.z += yv * w.z; acc.w += yv * w.w;
  }
  *(float4*)(zp + (kc * 16 + b) * 1024 + n) = acc;
}

// ---------------- k5b: reduce FC1 partials + bias; z, gelu(z) ----------------
__global__ __launch_bounds__(256) void k5b_red(const float* __restrict__ zp,
                                               const float* __restrict__ b1,
                                               float* __restrict__ z, float* __restrict__ g) {
  int gid = blockIdx.x * 256 + threadIdx.x;  // < 16384
  int b = gid >> 10, n = gid & 1023;
  float s = b1[n];
#pragma unroll
  for (int kc = 0; kc < 7; ++kc) s += zp[(kc * 16 + b) * 1024 + n];
  z[gid] = s;
  g[gid] = 0.5f * s * (1.f + erff(s * 0.70710678f));
}

// ---------------- k6: split-K FC2 partials ----------------
__global__ __launch_bounds__(256) void k6_fc2(const float* __restrict__ g,
                                              const float* __restrict__ W2,
                                              float* __restrict__ z2p) {
  __shared__ __align__(16) float gls[8 * 128];
  int t = threadIdx.x;
  int cb = blockIdx.x, bh = blockIdx.y, kc = blockIdx.z;  // (8,2,8)
  {
    int r = t / 32, q = t % 32;
    ((float4*)gls)[r * 32 + q] = *(const float4*)(g + (bh * 8 + r) * 1024 + kc * 128 + q * 4);
  }
  __syncthreads();
  int nq = t & 31, bl = t >> 5;
  int n = cb * 128 + nq * 4;
  int b = bh * 8 + bl;
  float4 acc = make_float4(0.f, 0.f, 0.f, 0.f);
  const float* grow = gls + bl * 128;
  for (int k = 0; k < 128; ++k) {
    float gv = grow[k];
    float4 w = *(const float4*)(W2 + (kc * 128 + k) * 1024 + n);
    acc.x += gv * w.x; acc.y += gv * w.y; acc.z += gv * w.z; acc.w += gv * w.w;
  }
  *(float4*)(z2p + (kc * 16 + b) * 1024 + n) = acc;
}

// ---------------- k7: reduce FC2 partials + residual + LayerNorm ----------------
__global__ __launch_bounds__(256) void k7_ln(const float* __restrict__ z,
                                             const float* __restrict__ z2p,
                                             const float* __restrict__ b2,
                                             const float* __restrict__ ln_g,
                                             const float* __restrict__ ln_b,
                                             float* __restrict__ out) {
  __shared__ float r1[256], r2[256];
  int t = threadIdx.x, b = blockIdx.x;
  float4 v = *(const float4*)(z + b * 1024 + t * 4);
  float4 bb2 = *(const float4*)(b2 + t * 4);
  v.x += bb2.x; v.y += bb2.y; v.z += bb2.z; v.w += bb2.w;
#pragma unroll
  for (int kc = 0; kc < 8; ++kc) {
    float4 p = *(const float4*)(z2p + (kc * 16 + b) * 1024 + t * 4);
    v.x += p.x; v.y += p.y; v.z += p.z; v.w += p.w;
  }
  r1[t] = v.x + v.y + v.z + v.w;
  r2[t] = v.x * v.x + v.y * v.y + v.z * v.z + v.w * v.w;
  __syncthreads();
  for (int s = 128; s > 0; s >>= 1) {
    if (t < s) {
      r1[t] += r1[t + s];
      r2[t] += r2[t + s];
    }
    __syncthreads();
  }
  float mu = r1[0] * (1.f / 1024.f);
  float var = r2[0] * (1.f / 1024.f) - mu * mu;
  float rstd = rsqrtf(var + 1e-5f);
  float4 gg = *(const float4*)(ln_g + t * 4);
  float4 bb = *(const float4*)(ln_b + t * 4);
  float4 o;
  o.x = (v.x - mu) * rstd * gg.x + bb.x;
  o.y = (v.y - mu) * rstd * gg.y + bb.y;
  o.z = (v.z - mu) * rstd * gg.z + bb.z;
  o.w = (v.w - mu) * rstd * gg.w + bb.w;
  *(float4*)(out + b * 1024 + t * 4) = o;
}

extern "C" void kernel_launch(void* const* d_in, const int* in_sizes, int n_in,
                              void* d_out, int out_size, void* d_ws, size_t ws_size,
                              hipStream_t stream) {
  (void)in_sizes; (void)n_in; (void)out_size; (void)ws_size;
  const float* x       = (const float*)d_in[0];
  const float* gat_W   = (const float*)d_in[1];
  const float* att_src = (const float*)d_in[2];
  const float* att_dst = (const float*)d_in[3];
  const float* gat_b   = (const float*)d_in[4];
  const float* conv1_w = (const float*)d_in[5];
  const float* conv2_w = (const float*)d_in[11];
  const float* projc_w = (const float*)d_in[17];
  const float* projc_b = (const float*)d_in[18];
  const float* W1      = (const float*)d_in[19];
  const float* b1      = (const float*)d_in[20];
  const float* W2      = (const float*)d_in[21];
  const float* b2      = (const float*)d_in[22];
  const float* ln_g    = (const float*)d_in[23];
  const float* ln_b    = (const float*)d_in[24];
  float* ws  = (float*)d_ws;
  float* out = (float*)d_out;

  hipLaunchKernelGGL(k0_prep, dim3(201), dim3(256), 0, stream, gat_W, conv1_w,
                     (const float*)d_in[6], (const float*)d_in[7], (const float*)d_in[8],
                     (const float*)d_in[9], (const float*)d_in[10], (const float*)d_in[12],
                     (const float*)d_in[13], (const float*)d_in[14], (const float*)d_in[15],
                     (const float*)d_in[16], ws);
  hipLaunchKernelGGL(k0b_w2t, dim3(6400), dim3(256), 0, stream, conv2_w, ws + WS_W2T);
  hipLaunchKernelGGL(k1_gemm_h, dim3(256, 4), dim3(256), 0, stream, x, ws + WS_WPAD, gat_b,
                     ws + WS_H, ws + WS_X1);
  hipLaunchKernelGGL(k1b_scores, dim3(4), dim3(256), 0, stream, ws + WS_H, att_src, att_dst,
                     ws + WS_AS, ws + WS_AD);
  hipLaunchKernelGGL(k1c_max, dim3(1), dim3(256), 0, stream, ws + WS_AS, ws + WS_MAXS);
  hipLaunchKernelGGL(kP, dim3(1024), dim3(256), 0, stream, ws + WS_AS, ws + WS_AD,
                     ws + WS_MAXS, ws + WS_P);
  hipLaunchKernelGGL(kAttn, dim3(16, 4, 4), dim3(256), 0, stream, ws + WS_P, ws + WS_H,
                     ws + WS_AP);
  hipLaunchKernelGGL(kAttnRed, dim3(1024), dim3(256), 0, stream, ws + WS_AP, x, gat_b,
                     ws + WS_X1);
  hipLaunchKernelGGL(k3_conv, dim3(16, 32), dim3(320), 0, stream, ws + WS_X1, ws + WS_W2T,
                     ws, ws + WS_Y3P);
  hipLaunchKernelGGL(k4_projred, dim3(16), dim3(256), 0, stream, ws + WS_Y3P, ws, projc_w,
                     projc_b, ws + WS_Y5);
  hipLaunchKernelGGL(k5_fc1, dim3(8, 2, 7), dim3(256), 0, stream, ws + WS_Y5, W1, ws + WS_ZP);
  hipLaunchKernelGGL(k5b_red, dim3(64), dim3(256), 0, stream, ws + WS_ZP, b1, ws + WS_Z,
                     ws + WS_G);
  hipLaunchKernelGGL(k6_fc2, dim3(8, 2, 8), dim3(256), 0, stream, ws + WS_G, W2, ws + WS_Z2P);
  hipLaunchKernelGGL(k7_ln, dim3(16), dim3(256), 0, stream, ws + WS_Z, ws + WS_Z2P, b2,
                     ln_g, ln_b, out);
}